// Round 6
// baseline (58.897 us; speedup 1.0000x reference)
//
#include <hip/hip_runtime.h>
#include <stdint.h>

#define L_DIM 1024
#define B_DIM 8
#define CIN   1024
#define COUT  1024
#define CCOND 256
#define KEXP  4
#define HID_DIM 64
#define TEMP_INV (1.0f/30.0f)

typedef float  f32x4 __attribute__((ext_vector_type(4)));
typedef __bf16 bf16x8 __attribute__((ext_vector_type(8)));

__device__ __forceinline__ ushort f2bf(float f) {
  union { float f; uint32_t u; } a; a.f = f;
  return (ushort)((a.u + 0x7fffu + ((a.u >> 16) & 1u)) >> 16);
}

// ---------- Kernel 1: att + bb (1 block, tiny LDS; R5-verified body) ----------
__global__ __launch_bounds__(256) void att_kernel(
                            const float* __restrict__ cond,
                            const float* __restrict__ fc1_w,
                            const float* __restrict__ fc1_b,
                            const float* __restrict__ fc2_w,
                            const float* __restrict__ fc2_b,
                            const float* __restrict__ bias,
                            float* __restrict__ att_out,
                            float* __restrict__ bb_out) {
  const int t = threadIdx.x;   // 256 threads
  __shared__ float clds[B_DIM][CCOND];   // 8 KB
  __shared__ float h[B_DIM][HID_DIM];    // 2 KB
  __shared__ float att[B_DIM][KEXP];
  #pragma unroll
  for (int ci = 0; ci < 2; ++ci) {
    int gi = ci * 256 + t;
    ((f32x4*)clds)[gi] = ((const f32x4*)cond)[gi];
  }
  __syncthreads();
  {
    const int j = t & 63, b0 = t >> 6;
    const f32x4* wrow = ((const f32x4*)fc1_w) + j * 64;   // direct global
    float a0 = 0.f, a1 = 0.f;
    #pragma unroll 8
    for (int c4 = 0; c4 < 64; ++c4) {
      f32x4 wv = wrow[c4];
      f32x4 ca = *(const f32x4*)&clds[b0][c4 * 4];
      f32x4 cb = *(const f32x4*)&clds[b0 + 4][c4 * 4];
      a0 += wv.x*ca.x + wv.y*ca.y + wv.z*ca.z + wv.w*ca.w;
      a1 += wv.x*cb.x + wv.y*cb.y + wv.z*cb.z + wv.w*cb.w;
    }
    float bj = fc1_b[j];
    h[b0][j]     = fmaxf(a0 + bj, 0.0f);
    h[b0 + 4][j] = fmaxf(a1 + bj, 0.0f);
  }
  __syncthreads();
  if (t < B_DIM * KEXP) {
    const int b = t >> 2, k = t & 3;
    const float* wp = fc2_w + k * HID_DIM;
    float s = fc2_b[k];
    #pragma unroll 8
    for (int j = 0; j < HID_DIM; ++j) s = fmaf(h[b][j], wp[j], s);
    att[b][k] = s * TEMP_INV;
  }
  __syncthreads();
  if (t < B_DIM) {
    const int b = t;
    float m = fmaxf(fmaxf(att[b][0], att[b][1]), fmaxf(att[b][2], att[b][3]));
    float e0 = expf(att[b][0] - m), e1 = expf(att[b][1] - m);
    float e2 = expf(att[b][2] - m), e3 = expf(att[b][3] - m);
    float inv = 1.0f / (e0 + e1 + e2 + e3);
    att[b][0] = e0 * inv; att[b][1] = e1 * inv;
    att[b][2] = e2 * inv; att[b][3] = e3 * inv;
    att_out[b*KEXP+0] = att[b][0]; att_out[b*KEXP+1] = att[b][1];
    att_out[b*KEXP+2] = att[b][2]; att_out[b*KEXP+3] = att[b][3];
  }
  __syncthreads();
  for (int idx = t; idx < B_DIM * COUT; idx += 256) {
    const int b = idx >> 10, o = idx & (COUT - 1);
    float s = att[b][0] * bias[o]        + att[b][1] * bias[COUT + o]
            + att[b][2] * bias[2*COUT+o] + att[b][3] * bias[3*COUT+o];
    bb_out[idx] = s;
  }
}

// ---------- Kernel 2: stream = xconv (1024 blocks) || wmix (256 blocks), 4:1 interleaved ----------
// bid%5==0 -> wmix (bids 0,5,...,1275), else xconv. Both streams run concurrently from t=0.
// att read via plain loads (ordering guaranteed by kernel boundary). Tiny LDS (128 B).
// Both bodies bitwise-identical to R0-verified arithmetic.
__global__ __launch_bounds__(256) void stream_kernel(
                            const float* __restrict__ x,
                            const float* __restrict__ weight,
                            const float* __restrict__ att,
                            ushort* __restrict__ xt,
                            ushort* __restrict__ wbb) {
  const int t = threadIdx.x;   // 256 threads
  const int bid = blockIdx.x;  // 0..1279
  __shared__ float satt[B_DIM * KEXP];

  if (bid % 5 != 0) {
    // -------- xconv path (R0-verbatim) --------
    const int xb = bid - 1 - bid / 5;    // 0..1023
    const int C4 = CIN / 4;
    const int r0 = xb * 8;
    const f32x4* xp = (const f32x4*)x;
    f32x4 v[8];
    #pragma unroll
    for (int i = 0; i < 8; ++i)
      v[i] = xp[(size_t)(r0 + i) * C4 + t];
    #pragma unroll
    for (int i = 0; i < 8; ++i) {
      const int r = r0 + i;
      const int b = r & (B_DIM - 1);
      const int l = r >> 3;
      ushort4 o;
      o.x = f2bf(v[i].x); o.y = f2bf(v[i].y); o.z = f2bf(v[i].z); o.w = f2bf(v[i].w);
      ((ushort4*)xt)[(b * L_DIM + l) * C4 + t] = o;
    }
    return;
  }

  // -------- wmix path: 256 blocks x 4 chunks (R0-verbatim arithmetic) --------
  const int wb = bid / 5;                     // 0..255
  const int total4 = COUT * CIN / 4;          // 262144
  const int base = wb * 1024 + t;             // chunk stride 256
  if (t < B_DIM * KEXP) satt[t] = att[t];
  __syncthreads();
  #pragma unroll
  for (int c = 0; c < 4; ++c) {
    const int idx = base + c * 256;
    f32x4 w0 = ((const f32x4*)weight)[idx];
    f32x4 w1 = ((const f32x4*)weight)[total4 + idx];
    f32x4 w2 = ((const f32x4*)weight)[2 * total4 + idx];
    f32x4 w3 = ((const f32x4*)weight)[3 * total4 + idx];
    #pragma unroll
    for (int b = 0; b < B_DIM; ++b) {
      f32x4 s = satt[b*4+0] * w0 + satt[b*4+1] * w1 + satt[b*4+2] * w2 + satt[b*4+3] * w3;
      ushort4 o;
      o.x = f2bf(s.x); o.y = f2bf(s.y); o.z = f2bf(s.z); o.w = f2bf(s.w);
      ((ushort4*)wbb)[b * total4 + idx] = o;
    }
  }
}

// ---------- Kernel 3: batched GEMM, 256x128 tile, counted-vmcnt 3-ring (R0-verbatim) ----------
#define GBM 256
#define GBN 128
#define GBK 64
#define GKT (CIN / GBK)   // 16

__global__ __launch_bounds__(512, 1) void gemm_kernel(
    const ushort* __restrict__ xt,    // (B, L, CIN) bf16
    const ushort* __restrict__ wbb,   // (B, COUT, CIN) bf16
    const float* __restrict__ bb,     // (B, COUT)
    float* __restrict__ out)          // (L, B, COUT) f32
{
  __shared__ ushort lds[3][(GBM + GBN) * GBK];   // 3 x 48 KB = 144 KB -> 1 block/CU

  const int bid = blockIdx.x;
  const int b  = bid & 7;             // batch -> XCD affinity
  const int tl = bid >> 3;            // 0..31
  const int mt = tl >> 3;             // 0..3  (L/256)
  const int nt = tl & 7;              // 0..7  (COUT/128)

  const int t = threadIdx.x;          // 0..511
  const int lane = t & 63;
  const int wid = t >> 6;             // 0..7
  const int wm = wid >> 1;            // 0..3 : rows wm*64
  const int wn = wid & 1;             // 0..1 : cols wn*64

  const ushort* __restrict__ Ag = xt  + (b * L_DIM + mt * GBM) * CIN;
  const ushort* __restrict__ Bg = wbb + (b * COUT  + nt * GBN) * CIN;

  const int srow = t >> 3;              // 0..63
  const int sg = (t & 7) ^ (srow & 7);  // pre-swizzled global 16B slot

  f32x4 acc[4][4] = {};

  auto stage = [&](int bf, int kt) {
    #pragma unroll
    for (int i = 0; i < 4; ++i) {       // A: 256 rows
      const int r = i * 64 + srow;
      __builtin_amdgcn_global_load_lds(
        (const __attribute__((address_space(1))) uint32_t*)(Ag + r * CIN + kt * GBK + sg * 8),
        (__attribute__((address_space(3))) uint32_t*)(&lds[bf][i * 4096 + t * 8]), 16, 0, 0);
    }
    #pragma unroll
    for (int i = 0; i < 2; ++i) {       // B: 128 rows
      const int r = i * 64 + srow;
      __builtin_amdgcn_global_load_lds(
        (const __attribute__((address_space(1))) uint32_t*)(Bg + r * CIN + kt * GBK + sg * 8),
        (__attribute__((address_space(3))) uint32_t*)(&lds[bf][GBM * GBK + i * 4096 + t * 8]), 16, 0, 0);
    }
  };

  stage(0, 0);
  stage(1, 1);

  const int kg = lane >> 4;           // k-subgroup 0..3
  const int rr = lane & 15;

  #pragma unroll
  for (int kt = 0; kt < GKT; ++kt) {
    if (kt < GKT - 1) { asm volatile("s_waitcnt vmcnt(6)" ::: "memory"); }
    else              { asm volatile("s_waitcnt vmcnt(0)" ::: "memory"); }
    __builtin_amdgcn_sched_barrier(0);
    __builtin_amdgcn_s_barrier();       // raw barrier: no vmcnt drain
    __builtin_amdgcn_sched_barrier(0);
    if (kt + 2 < GKT) stage((kt + 2) % 3, kt + 2);
    __builtin_amdgcn_sched_barrier(0);

    const ushort* Ab = &lds[kt % 3][0];
    const ushort* Bb = &lds[kt % 3][GBM * GBK];
    bf16x8 af[4][2], bfv[4][2];
    #pragma unroll
    for (int kk = 0; kk < 2; ++kk) {
      const int sl = ((kk << 2) | kg) ^ (rr & 7);
      #pragma unroll
      for (int m = 0; m < 4; ++m)
        af[m][kk] = *(const bf16x8*)(Ab + (wm * 64 + m * 16 + rr) * GBK + sl * 8);
      #pragma unroll
      for (int n = 0; n < 4; ++n)
        bfv[n][kk] = *(const bf16x8*)(Bb + (wn * 64 + n * 16 + rr) * GBK + sl * 8);
    }
    __builtin_amdgcn_s_setprio(1);
    #pragma unroll
    for (int kk = 0; kk < 2; ++kk)
      #pragma unroll
      for (int m = 0; m < 4; ++m)
        #pragma unroll
        for (int n = 0; n < 4; ++n)
          acc[m][n] = __builtin_amdgcn_mfma_f32_16x16x32_bf16(af[m][kk], bfv[n][kk], acc[m][n], 0, 0, 0);
    __builtin_amdgcn_s_setprio(0);
  }

  const int colbase = nt * GBN + wn * 64;
  const int rowbase = mt * GBM + wm * 64;
  float bcol[4];
  #pragma unroll
  for (int n = 0; n < 4; ++n) bcol[n] = bb[b * COUT + colbase + n * 16 + rr];
  #pragma unroll
  for (int m = 0; m < 4; ++m) {
    #pragma unroll
    for (int j = 0; j < 4; ++j) {
      int row = rowbase + m * 16 + kg * 4 + j;
      float* op = out + row * (B_DIM * COUT) + b * COUT + colbase;
      #pragma unroll
      for (int n = 0; n < 4; ++n)
        op[n * 16 + rr] = acc[m][n][j] + bcol[n];
    }
  }
}

// ---------------- launch ----------------
extern "C" void kernel_launch(void* const* d_in, const int* in_sizes, int n_in,
                              void* d_out, int out_size, void* d_ws, size_t ws_size,
                              hipStream_t stream) {
  const float* x      = (const float*)d_in[0];
  const float* cond   = (const float*)d_in[1];
  const float* fc1_w  = (const float*)d_in[2];
  const float* fc1_b  = (const float*)d_in[3];
  const float* fc2_w  = (const float*)d_in[4];
  const float* fc2_b  = (const float*)d_in[5];
  const float* weight = (const float*)d_in[6];
  const float* bias   = (const float*)d_in[7];
  float* out = (float*)d_out;

  char* ws = (char*)d_ws;
  float*  att = (float*)ws;                                  // 32 f
  float*  bbp = (float*)(ws + 256);                          // 8192 f
  ushort* xt  = (ushort*)(ws + 65536);                       // 16 MB
  ushort* wbb = (ushort*)(ws + 65536 + (size_t)L_DIM * B_DIM * CIN * 2); // 16 MB

  hipLaunchKernelGGL(att_kernel, dim3(1), dim3(256), 0, stream,
                     cond, fc1_w, fc1_b, fc2_w, fc2_b, bias, att, bbp);
  hipLaunchKernelGGL(stream_kernel, dim3(1280), dim3(256), 0, stream,
                     x, weight, att, xt, wbb);
  hipLaunchKernelGGL(gemm_kernel, dim3(B_DIM * (L_DIM / GBM) * (COUT / GBN)), dim3(512), 0, stream,
                     xt, wbb, bbp, out);
}

// Round 7
// 56.060 us; speedup vs baseline: 1.0506x; 1.0506x over previous
//
#include <hip/hip_runtime.h>
#include <stdint.h>

#define L_DIM 1024
#define B_DIM 8
#define CIN   1024
#define COUT  1024
#define CCOND 256
#define KEXP  4
#define HID_DIM 64
#define TEMP_INV (1.0f/30.0f)

typedef float  f32x4 __attribute__((ext_vector_type(4)));
typedef __bf16 bf16x8 __attribute__((ext_vector_type(8)));

__device__ __forceinline__ ushort f2bf(float f) {
  union { float f; uint32_t u; } a; a.f = f;
  return (ushort)((a.u + 0x7fffu + ((a.u >> 16) & 1u)) >> 16);
}

// ---------- Kernel 1: prep = cond_att (block 0, TINY-LDS body, R5/R6-verified) || xconv ----------
// Single change vs R0: block 0 reads fc1_w direct from global (no 66 KB wlds stage),
// so LDS_Block_Size drops 77312 -> ~10.4 KB and the 1024 xconv streaming blocks go
// from 2 blocks/CU to full occupancy. All arithmetic bitwise-identical to R0.
__global__ __launch_bounds__(256) void prep_kernel(
                            const float* __restrict__ x,
                            const float* __restrict__ cond,
                            const float* __restrict__ fc1_w,
                            const float* __restrict__ fc1_b,
                            const float* __restrict__ fc2_w,
                            const float* __restrict__ fc2_b,
                            const float* __restrict__ bias,
                            ushort* __restrict__ xt,
                            float* __restrict__ att_out,
                            float* __restrict__ bb_out) {
  const int t = threadIdx.x;   // 256 threads
  __shared__ float clds[B_DIM][CCOND];   // 8 KB
  __shared__ float h[B_DIM][HID_DIM];    // 2 KB
  __shared__ float att[B_DIM][KEXP];
  if (blockIdx.x == 0) {
    #pragma unroll
    for (int ci = 0; ci < 2; ++ci) {
      int gi = ci * 256 + t;
      ((f32x4*)clds)[gi] = ((const f32x4*)cond)[gi];
    }
    __syncthreads();
    {
      const int j = t & 63, b0 = t >> 6;
      const f32x4* wrow = ((const f32x4*)fc1_w) + j * 64;   // direct global (L2-served)
      float a0 = 0.f, a1 = 0.f;
      #pragma unroll 8
      for (int c4 = 0; c4 < 64; ++c4) {
        f32x4 wv = wrow[c4];
        f32x4 ca = *(const f32x4*)&clds[b0][c4 * 4];
        f32x4 cb = *(const f32x4*)&clds[b0 + 4][c4 * 4];
        a0 += wv.x*ca.x + wv.y*ca.y + wv.z*ca.z + wv.w*ca.w;
        a1 += wv.x*cb.x + wv.y*cb.y + wv.z*cb.z + wv.w*cb.w;
      }
      float bj = fc1_b[j];
      h[b0][j]     = fmaxf(a0 + bj, 0.0f);
      h[b0 + 4][j] = fmaxf(a1 + bj, 0.0f);
    }
    __syncthreads();
    if (t < B_DIM * KEXP) {
      const int b = t >> 2, k = t & 3;
      const float* wp = fc2_w + k * HID_DIM;
      float s = fc2_b[k];
      #pragma unroll 8
      for (int j = 0; j < HID_DIM; ++j) s = fmaf(h[b][j], wp[j], s);
      att[b][k] = s * TEMP_INV;
    }
    __syncthreads();
    if (t < B_DIM) {
      const int b = t;
      float m = fmaxf(fmaxf(att[b][0], att[b][1]), fmaxf(att[b][2], att[b][3]));
      float e0 = expf(att[b][0] - m), e1 = expf(att[b][1] - m);
      float e2 = expf(att[b][2] - m), e3 = expf(att[b][3] - m);
      float inv = 1.0f / (e0 + e1 + e2 + e3);
      att[b][0] = e0 * inv; att[b][1] = e1 * inv;
      att[b][2] = e2 * inv; att[b][3] = e3 * inv;
      att_out[b*KEXP+0] = att[b][0]; att_out[b*KEXP+1] = att[b][1];
      att_out[b*KEXP+2] = att[b][2]; att_out[b*KEXP+3] = att[b][3];
    }
    __syncthreads();
    for (int idx = t; idx < B_DIM * COUT; idx += 256) {
      const int b = idx >> 10, o = idx & (COUT - 1);
      float s = att[b][0] * bias[o]        + att[b][1] * bias[COUT + o]
              + att[b][2] * bias[2*COUT+o] + att[b][3] * bias[3*COUT+o];
      bb_out[idx] = s;
    }
  } else {
    // -------- xconv path (R0-verbatim) --------
    const int C4 = CIN / 4;
    const int r0 = (blockIdx.x - 1) * 8;
    const f32x4* xp = (const f32x4*)x;
    f32x4 v[8];
    #pragma unroll
    for (int i = 0; i < 8; ++i)
      v[i] = xp[(size_t)(r0 + i) * C4 + t];
    #pragma unroll
    for (int i = 0; i < 8; ++i) {
      const int r = r0 + i;
      const int b = r & (B_DIM - 1);
      const int l = r >> 3;
      ushort4 o;
      o.x = f2bf(v[i].x); o.y = f2bf(v[i].y); o.z = f2bf(v[i].z); o.w = f2bf(v[i].w);
      ((ushort4*)xt)[(b * L_DIM + l) * C4 + t] = o;
    }
  }
}

// ---------- Kernel 2: w_bb[b] = sum_k att[b][k]*weight[k], bf16 (R0-verbatim) ----------
__global__ void wmix_kernel(const float* __restrict__ weight,
                            const float* __restrict__ att,
                            ushort* __restrict__ wbb) {
  __shared__ float satt[B_DIM * KEXP];
  if (threadIdx.x < B_DIM * KEXP) satt[threadIdx.x] = att[threadIdx.x];
  __syncthreads();
  const int total4 = COUT * CIN / 4;   // 262144
  int idx = blockIdx.x * blockDim.x + threadIdx.x;
  if (idx >= total4) return;
  f32x4 w0 = ((const f32x4*)weight)[idx];
  f32x4 w1 = ((const f32x4*)weight)[total4 + idx];
  f32x4 w2 = ((const f32x4*)weight)[2 * total4 + idx];
  f32x4 w3 = ((const f32x4*)weight)[3 * total4 + idx];
  #pragma unroll
  for (int b = 0; b < B_DIM; ++b) {
    f32x4 s = satt[b*4+0] * w0 + satt[b*4+1] * w1 + satt[b*4+2] * w2 + satt[b*4+3] * w3;
    ushort4 o;
    o.x = f2bf(s.x); o.y = f2bf(s.y); o.z = f2bf(s.z); o.w = f2bf(s.w);
    ((ushort4*)wbb)[b * total4 + idx] = o;
  }
}

// ---------- Kernel 3: batched GEMM, 256x128 tile, counted-vmcnt 3-ring (R0-verbatim) ----------
#define GBM 256
#define GBN 128
#define GBK 64
#define GKT (CIN / GBK)   // 16

__global__ __launch_bounds__(512, 1) void gemm_kernel(
    const ushort* __restrict__ xt,    // (B, L, CIN) bf16
    const ushort* __restrict__ wbb,   // (B, COUT, CIN) bf16
    const float* __restrict__ bb,     // (B, COUT)
    float* __restrict__ out)          // (L, B, COUT) f32
{
  __shared__ ushort lds[3][(GBM + GBN) * GBK];   // 3 x 48 KB = 144 KB -> 1 block/CU

  const int bid = blockIdx.x;
  const int b  = bid & 7;             // batch -> XCD affinity
  const int tl = bid >> 3;            // 0..31
  const int mt = tl >> 3;             // 0..3  (L/256)
  const int nt = tl & 7;              // 0..7  (COUT/128)

  const int t = threadIdx.x;          // 0..511
  const int lane = t & 63;
  const int wid = t >> 6;             // 0..7
  const int wm = wid >> 1;            // 0..3 : rows wm*64
  const int wn = wid & 1;             // 0..1 : cols wn*64

  const ushort* __restrict__ Ag = xt  + (b * L_DIM + mt * GBM) * CIN;
  const ushort* __restrict__ Bg = wbb + (b * COUT  + nt * GBN) * CIN;

  const int srow = t >> 3;              // 0..63
  const int sg = (t & 7) ^ (srow & 7);  // pre-swizzled global 16B slot

  f32x4 acc[4][4] = {};

  auto stage = [&](int bf, int kt) {
    #pragma unroll
    for (int i = 0; i < 4; ++i) {       // A: 256 rows
      const int r = i * 64 + srow;
      __builtin_amdgcn_global_load_lds(
        (const __attribute__((address_space(1))) uint32_t*)(Ag + r * CIN + kt * GBK + sg * 8),
        (__attribute__((address_space(3))) uint32_t*)(&lds[bf][i * 4096 + t * 8]), 16, 0, 0);
    }
    #pragma unroll
    for (int i = 0; i < 2; ++i) {       // B: 128 rows
      const int r = i * 64 + srow;
      __builtin_amdgcn_global_load_lds(
        (const __attribute__((address_space(1))) uint32_t*)(Bg + r * CIN + kt * GBK + sg * 8),
        (__attribute__((address_space(3))) uint32_t*)(&lds[bf][GBM * GBK + i * 4096 + t * 8]), 16, 0, 0);
    }
  };

  stage(0, 0);
  stage(1, 1);

  const int kg = lane >> 4;           // k-subgroup 0..3
  const int rr = lane & 15;

  #pragma unroll
  for (int kt = 0; kt < GKT; ++kt) {
    if (kt < GKT - 1) { asm volatile("s_waitcnt vmcnt(6)" ::: "memory"); }
    else              { asm volatile("s_waitcnt vmcnt(0)" ::: "memory"); }
    __builtin_amdgcn_sched_barrier(0);
    __builtin_amdgcn_s_barrier();       // raw barrier: no vmcnt drain
    __builtin_amdgcn_sched_barrier(0);
    if (kt + 2 < GKT) stage((kt + 2) % 3, kt + 2);
    __builtin_amdgcn_sched_barrier(0);

    const ushort* Ab = &lds[kt % 3][0];
    const ushort* Bb = &lds[kt % 3][GBM * GBK];
    bf16x8 af[4][2], bfv[4][2];
    #pragma unroll
    for (int kk = 0; kk < 2; ++kk) {
      const int sl = ((kk << 2) | kg) ^ (rr & 7);
      #pragma unroll
      for (int m = 0; m < 4; ++m)
        af[m][kk] = *(const bf16x8*)(Ab + (wm * 64 + m * 16 + rr) * GBK + sl * 8);
      #pragma unroll
      for (int n = 0; n < 4; ++n)
        bfv[n][kk] = *(const bf16x8*)(Bb + (wn * 64 + n * 16 + rr) * GBK + sl * 8);
    }
    __builtin_amdgcn_s_setprio(1);
    #pragma unroll
    for (int kk = 0; kk < 2; ++kk)
      #pragma unroll
      for (int m = 0; m < 4; ++m)
        #pragma unroll
        for (int n = 0; n < 4; ++n)
          acc[m][n] = __builtin_amdgcn_mfma_f32_16x16x32_bf16(af[m][kk], bfv[n][kk], acc[m][n], 0, 0, 0);
    __builtin_amdgcn_s_setprio(0);
  }

  const int colbase = nt * GBN + wn * 64;
  const int rowbase = mt * GBM + wm * 64;
  float bcol[4];
  #pragma unroll
  for (int n = 0; n < 4; ++n) bcol[n] = bb[b * COUT + colbase + n * 16 + rr];
  #pragma unroll
  for (int m = 0; m < 4; ++m) {
    #pragma unroll
    for (int j = 0; j < 4; ++j) {
      int row = rowbase + m * 16 + kg * 4 + j;
      float* op = out + row * (B_DIM * COUT) + b * COUT + colbase;
      #pragma unroll
      for (int n = 0; n < 4; ++n)
        op[n * 16 + rr] = acc[m][n][j] + bcol[n];
    }
  }
}

// ---------------- launch ----------------
extern "C" void kernel_launch(void* const* d_in, const int* in_sizes, int n_in,
                              void* d_out, int out_size, void* d_ws, size_t ws_size,
                              hipStream_t stream) {
  const float* x      = (const float*)d_in[0];
  const float* cond   = (const float*)d_in[1];
  const float* fc1_w  = (const float*)d_in[2];
  const float* fc1_b  = (const float*)d_in[3];
  const float* fc2_w  = (const float*)d_in[4];
  const float* fc2_b  = (const float*)d_in[5];
  const float* weight = (const float*)d_in[6];
  const float* bias   = (const float*)d_in[7];
  float* out = (float*)d_out;

  char* ws = (char*)d_ws;
  float*  att = (float*)ws;                                  // 32 f
  float*  bbp = (float*)(ws + 256);                          // 8192 f
  ushort* xt  = (ushort*)(ws + 65536);                       // 16 MB
  ushort* wbb = (ushort*)(ws + 65536 + (size_t)L_DIM * B_DIM * CIN * 2); // 16 MB

  hipLaunchKernelGGL(prep_kernel, dim3(1 + (L_DIM * B_DIM) / 8), dim3(256), 0, stream,
                     x, cond, fc1_w, fc1_b, fc2_w, fc2_b, bias, xt, att, bbp);
  hipLaunchKernelGGL(wmix_kernel, dim3((COUT * CIN / 4) / 256), dim3(256), 0, stream,
                     weight, att, wbb);
  hipLaunchKernelGGL(gemm_kernel, dim3(B_DIM * (L_DIM / GBM) * (COUT / GBN)), dim3(512), 0, stream,
                     xt, wbb, bbp, out);
}

// Round 8
// 46.471 us; speedup vs baseline: 1.2674x; 1.2064x over previous
//
#include <hip/hip_runtime.h>
#include <stdint.h>

#define L_DIM 1024
#define B_DIM 8
#define CIN   1024
#define COUT  1024
#define CCOND 256
#define KEXP  4
#define HID_DIM 64
#define TEMP_INV (1.0f/30.0f)

typedef float  f32x4 __attribute__((ext_vector_type(4)));
typedef __bf16 bf16x8 __attribute__((ext_vector_type(8)));

__device__ __forceinline__ ushort f2bf(float f) {
  union { float f; uint32_t u; } a; a.f = f;
  return (ushort)((a.u + 0x7fffu + ((a.u >> 16) & 1u)) >> 16);
}

// ---------- Kernel 1: prep = cond_att (block 0, LDS-staged, coalesced fc1_w) || xconv ----------
// NOTE (R7 lesson): the 66 KB wlds stage IS the coalesced load of fc1_w. Removing it
// (direct per-row global reads, lane-stride 1 KB) makes block 0 the kernel's critical
// path (+9 us). Keep the stage.
__global__ __launch_bounds__(256) void prep_kernel(
                            const float* __restrict__ x,
                            const float* __restrict__ cond,
                            const float* __restrict__ fc1_w,
                            const float* __restrict__ fc1_b,
                            const float* __restrict__ fc2_w,
                            const float* __restrict__ fc2_b,
                            const float* __restrict__ bias,
                            ushort* __restrict__ xt,
                            float* __restrict__ att_out,
                            float* __restrict__ bb_out) {
  const int t = threadIdx.x;   // 256 threads
  if (blockIdx.x == 0) {
    __shared__ float wlds[HID_DIM][CCOND + 4];  // 64 x 260 f32 = 66.6 KB
    __shared__ float clds[B_DIM][CCOND];        // 8 KB
    __shared__ float h[B_DIM][HID_DIM];
    __shared__ float att[B_DIM][KEXP];
    #pragma unroll
    for (int ci = 0; ci < 16; ++ci) {
      int gi = ci * 256 + t;
      f32x4 v = ((const f32x4*)fc1_w)[gi];
      int j = gi >> 6, c4 = gi & 63;
      *(f32x4*)&wlds[j][c4 * 4] = v;
    }
    #pragma unroll
    for (int ci = 0; ci < 2; ++ci) {
      int gi = ci * 256 + t;
      ((f32x4*)clds)[gi] = ((const f32x4*)cond)[gi];
    }
    __syncthreads();
    {
      const int j = t & 63, b0 = t >> 6;
      float a0 = 0.f, a1 = 0.f;
      #pragma unroll 8
      for (int c4 = 0; c4 < 64; ++c4) {
        f32x4 wv = *(const f32x4*)&wlds[j][c4 * 4];
        f32x4 ca = *(const f32x4*)&clds[b0][c4 * 4];
        f32x4 cb = *(const f32x4*)&clds[b0 + 4][c4 * 4];
        a0 += wv.x*ca.x + wv.y*ca.y + wv.z*ca.z + wv.w*ca.w;
        a1 += wv.x*cb.x + wv.y*cb.y + wv.z*cb.z + wv.w*cb.w;
      }
      float bj = fc1_b[j];
      h[b0][j]     = fmaxf(a0 + bj, 0.0f);
      h[b0 + 4][j] = fmaxf(a1 + bj, 0.0f);
    }
    __syncthreads();
    if (t < B_DIM * KEXP) {
      const int b = t >> 2, k = t & 3;
      const float* wp = fc2_w + k * HID_DIM;
      float s = fc2_b[k];
      #pragma unroll 8
      for (int j = 0; j < HID_DIM; ++j) s = fmaf(h[b][j], wp[j], s);
      att[b][k] = s * TEMP_INV;
    }
    __syncthreads();
    if (t < B_DIM) {
      const int b = t;
      float m = fmaxf(fmaxf(att[b][0], att[b][1]), fmaxf(att[b][2], att[b][3]));
      float e0 = expf(att[b][0] - m), e1 = expf(att[b][1] - m);
      float e2 = expf(att[b][2] - m), e3 = expf(att[b][3] - m);
      float inv = 1.0f / (e0 + e1 + e2 + e3);
      att[b][0] = e0 * inv; att[b][1] = e1 * inv;
      att[b][2] = e2 * inv; att[b][3] = e3 * inv;
      att_out[b*KEXP+0] = att[b][0]; att_out[b*KEXP+1] = att[b][1];
      att_out[b*KEXP+2] = att[b][2]; att_out[b*KEXP+3] = att[b][3];
    }
    __syncthreads();
    for (int idx = t; idx < B_DIM * COUT; idx += 256) {
      const int b = idx >> 10, o = idx & (COUT - 1);
      float s = att[b][0] * bias[o]        + att[b][1] * bias[COUT + o]
              + att[b][2] * bias[2*COUT+o] + att[b][3] * bias[3*COUT+o];
      bb_out[idx] = s;
    }
  } else {
    const int C4 = CIN / 4;
    const int r0 = (blockIdx.x - 1) * 8;
    const f32x4* xp = (const f32x4*)x;
    f32x4 v[8];
    #pragma unroll
    for (int i = 0; i < 8; ++i)
      v[i] = xp[(size_t)(r0 + i) * C4 + t];
    #pragma unroll
    for (int i = 0; i < 8; ++i) {
      const int r = r0 + i;
      const int b = r & (B_DIM - 1);
      const int l = r >> 3;
      ushort4 o;
      o.x = f2bf(v[i].x); o.y = f2bf(v[i].y); o.z = f2bf(v[i].z); o.w = f2bf(v[i].w);
      ((ushort4*)xt)[(b * L_DIM + l) * C4 + t] = o;
    }
  }
}

// ---------- Kernel 2: w_bb[b] = sum_k att[b][k]*weight[k], bf16 (R0-verified) ----------
__global__ void wmix_kernel(const float* __restrict__ weight,
                            const float* __restrict__ att,
                            ushort* __restrict__ wbb) {
  __shared__ float satt[B_DIM * KEXP];
  if (threadIdx.x < B_DIM * KEXP) satt[threadIdx.x] = att[threadIdx.x];
  __syncthreads();
  const int total4 = COUT * CIN / 4;   // 262144
  int idx = blockIdx.x * blockDim.x + threadIdx.x;
  if (idx >= total4) return;
  f32x4 w0 = ((const f32x4*)weight)[idx];
  f32x4 w1 = ((const f32x4*)weight)[total4 + idx];
  f32x4 w2 = ((const f32x4*)weight)[2 * total4 + idx];
  f32x4 w3 = ((const f32x4*)weight)[3 * total4 + idx];
  #pragma unroll
  for (int b = 0; b < B_DIM; ++b) {
    f32x4 s = satt[b*4+0] * w0 + satt[b*4+1] * w1 + satt[b*4+2] * w2 + satt[b*4+3] * w3;
    ushort4 o;
    o.x = f2bf(s.x); o.y = f2bf(s.y); o.z = f2bf(s.z); o.w = f2bf(s.w);
    ((ushort4*)wbb)[b * total4 + idx] = o;
  }
}

// ---------- Kernel 3: batched GEMM, 256x128 tile, counted-vmcnt 3-ring pipeline ----------
// out[:,b,:] = x_t[b] @ w_bb[b]^T + bb[b].  8 waves (4M x 2N), per-wave 64x64.
#define GBM 256
#define GBN 128
#define GBK 64
#define GKT (CIN / GBK)   // 16

__global__ __launch_bounds__(512, 1) void gemm_kernel(
    const ushort* __restrict__ xt,    // (B, L, CIN) bf16
    const ushort* __restrict__ wbb,   // (B, COUT, CIN) bf16
    const float* __restrict__ bb,     // (B, COUT)
    float* __restrict__ out)          // (L, B, COUT) f32
{
  __shared__ ushort lds[3][(GBM + GBN) * GBK];   // 3 x 48 KB = 144 KB -> 1 block/CU

  const int bid = blockIdx.x;
  const int b  = bid & 7;             // batch -> XCD affinity
  const int tl = bid >> 3;            // 0..31
  const int mt = tl >> 3;             // 0..3  (L/256)
  const int nt = tl & 7;              // 0..7  (COUT/128)

  const int t = threadIdx.x;          // 0..511
  const int lane = t & 63;
  const int wid = t >> 6;             // 0..7
  const int wm = wid >> 1;            // 0..3 : rows wm*64
  const int wn = wid & 1;             // 0..1 : cols wn*64

  const ushort* __restrict__ Ag = xt  + (b * L_DIM + mt * GBM) * CIN;
  const ushort* __restrict__ Bg = wbb + (b * COUT  + nt * GBN) * CIN;

  // staging: 64 rows x 8 slots(16B) per instr (512 threads).
  // LDS dest linear; source slot XOR-pre-swizzled: LDS[r][s] = global slot s^(r&7).
  const int srow = t >> 3;              // 0..63
  const int sg = (t & 7) ^ (srow & 7);  // pre-swizzled global 16B slot

  f32x4 acc[4][4] = {};

  auto stage = [&](int bf, int kt) {
    #pragma unroll
    for (int i = 0; i < 4; ++i) {       // A: 256 rows
      const int r = i * 64 + srow;
      __builtin_amdgcn_global_load_lds(
        (const __attribute__((address_space(1))) uint32_t*)(Ag + r * CIN + kt * GBK + sg * 8),
        (__attribute__((address_space(3))) uint32_t*)(&lds[bf][i * 4096 + t * 8]), 16, 0, 0);
    }
    #pragma unroll
    for (int i = 0; i < 2; ++i) {       // B: 128 rows
      const int r = i * 64 + srow;
      __builtin_amdgcn_global_load_lds(
        (const __attribute__((address_space(1))) uint32_t*)(Bg + r * CIN + kt * GBK + sg * 8),
        (__attribute__((address_space(3))) uint32_t*)(&lds[bf][GBM * GBK + i * 4096 + t * 8]), 16, 0, 0);
    }
  };

  // prologue: prefetch tiles 0 and 1 (6 loads each)
  stage(0, 0);
  stage(1, 1);

  const int kg = lane >> 4;           // k-subgroup 0..3
  const int rr = lane & 15;

  #pragma unroll
  for (int kt = 0; kt < GKT; ++kt) {
    // counted wait: keep the newest tile's 6 loads in flight (drain only at the end)
    if (kt < GKT - 1) { asm volatile("s_waitcnt vmcnt(6)" ::: "memory"); }
    else              { asm volatile("s_waitcnt vmcnt(0)" ::: "memory"); }
    __builtin_amdgcn_sched_barrier(0);
    __builtin_amdgcn_s_barrier();       // raw barrier: no vmcnt drain
    __builtin_amdgcn_sched_barrier(0);
    if (kt + 2 < GKT) stage((kt + 2) % 3, kt + 2);   // safe: buf last read in iter kt-1
    __builtin_amdgcn_sched_barrier(0);

    const ushort* Ab = &lds[kt % 3][0];
    const ushort* Bb = &lds[kt % 3][GBM * GBK];
    bf16x8 af[4][2], bfv[4][2];
    #pragma unroll
    for (int kk = 0; kk < 2; ++kk) {
      const int sl = ((kk << 2) | kg) ^ (rr & 7);
      #pragma unroll
      for (int m = 0; m < 4; ++m)
        af[m][kk] = *(const bf16x8*)(Ab + (wm * 64 + m * 16 + rr) * GBK + sl * 8);
      #pragma unroll
      for (int n = 0; n < 4; ++n)
        bfv[n][kk] = *(const bf16x8*)(Bb + (wn * 64 + n * 16 + rr) * GBK + sl * 8);
    }
    __builtin_amdgcn_s_setprio(1);
    #pragma unroll
    for (int kk = 0; kk < 2; ++kk)
      #pragma unroll
      for (int m = 0; m < 4; ++m)
        #pragma unroll
        for (int n = 0; n < 4; ++n)
          acc[m][n] = __builtin_amdgcn_mfma_f32_16x16x32_bf16(af[m][kk], bfv[n][kk], acc[m][n], 0, 0, 0);
    __builtin_amdgcn_s_setprio(0);
  }

  // epilogue: C/D layout col = lane&15, row = (lane>>4)*4 + reg (verified R0-R8)
  const int colbase = nt * GBN + wn * 64;
  const int rowbase = mt * GBM + wm * 64;
  float bcol[4];
  #pragma unroll
  for (int n = 0; n < 4; ++n) bcol[n] = bb[b * COUT + colbase + n * 16 + rr];
  #pragma unroll
  for (int m = 0; m < 4; ++m) {
    #pragma unroll
    for (int j = 0; j < 4; ++j) {
      int row = rowbase + m * 16 + kg * 4 + j;
      float* op = out + row * (B_DIM * COUT) + b * COUT + colbase;
      #pragma unroll
      for (int n = 0; n < 4; ++n)
        op[n * 16 + rr] = acc[m][n][j] + bcol[n];
    }
  }
}

// ---------------- launch ----------------
extern "C" void kernel_launch(void* const* d_in, const int* in_sizes, int n_in,
                              void* d_out, int out_size, void* d_ws, size_t ws_size,
                              hipStream_t stream) {
  const float* x      = (const float*)d_in[0];
  const float* cond   = (const float*)d_in[1];
  const float* fc1_w  = (const float*)d_in[2];
  const float* fc1_b  = (const float*)d_in[3];
  const float* fc2_w  = (const float*)d_in[4];
  const float* fc2_b  = (const float*)d_in[5];
  const float* weight = (const float*)d_in[6];
  const float* bias   = (const float*)d_in[7];
  float* out = (float*)d_out;

  char* ws = (char*)d_ws;
  float*  att = (float*)ws;                                  // 32 f
  float*  bbp = (float*)(ws + 256);                          // 8192 f
  ushort* xt  = (ushort*)(ws + 65536);                       // 16 MB
  ushort* wbb = (ushort*)(ws + 65536 + (size_t)L_DIM * B_DIM * CIN * 2); // 16 MB

  hipLaunchKernelGGL(prep_kernel, dim3(1 + (L_DIM * B_DIM) / 8), dim3(256), 0, stream,
                     x, cond, fc1_w, fc1_b, fc2_w, fc2_b, bias, xt, att, bbp);
  hipLaunchKernelGGL(wmix_kernel, dim3((COUT * CIN / 4) / 256), dim3(256), 0, stream,
                     weight, att, wbb);
  hipLaunchKernelGGL(gemm_kernel, dim3(B_DIM * (L_DIM / GBM) * (COUT / GBN)), dim3(512), 0, stream,
                     xt, wbb, bbp, out);
}